// Round 5
// baseline (1566.821 us; speedup 1.0000x reference)
//
#include <hip/hip_runtime.h>
#include <hip/hip_bf16.h>

// CRF-as-RNN mean-field on MI355X. B=2, L=21, C=3, H=W=96, N=9216, NITERS=5.
//
// w[n][m] = exp2(gs[m] + f_n . fs[m]); per iter P[n][l] = sum_m w[n][m]*MQ[l][m]
// via bf16 MFMA 16x16x32. W generated on the fly into LDS (A-tile); MQ bf16
// staged as B-tile. B-row 21 is constant 1.0 so MFMA col 21 = rowsum(W) free.
// KEY CHANGE vs R4: SINGLE LDS buffer (12.3 KB -> static 8 blocks/CU, the
// wave-slot max) instead of double-buffered 24.6 KB (6 blocks static, ~3
// measured). Rounds R1-R4 show the kernel is latency-bound with ~25%
// per-SIMD issue utilization; the fix is wave TLP, not deeper per-wave
// pipelining. Keep thin lgkm-only barriers (no vmcnt drain) + dual named
// prefetch register sets (loads get >= 1 tile of slack). 2 barriers/tile.
// msg = P/P[21]; Q = softmax_l(-(E0+msg)); MQ = Mu@Q (bf16).

#define BB 2
#define LL 21
#define LP (LL + 1)   // Ppart rows: 21 msg cols + 1 rowsum col
#define NNPX 9216
#define NITERS 5
#define LOG2E 1.4426950408889634f

// raw barrier: waits LDS ops of this wave, syncs, does NOT drain vmcnt
#define BARRIER() asm volatile("s_waitcnt lgkmcnt(0)\n\ts_barrier" ::: "memory")

typedef __attribute__((ext_vector_type(8))) short short8;
typedef __attribute__((ext_vector_type(4))) float f32x4;
typedef __attribute__((ext_vector_type(4))) unsigned int u32x4;

static __device__ inline unsigned int pk_bf16(float a, float b) {
    __hip_bfloat162 h = __float22bfloat162_rn(make_float2(a, b));
    unsigned int u;
    __builtin_memcpy(&u, &h, 4);
    return u;
}

// ---------------- prep: features + Q0 + MQ0(bf16) ----------------
__global__ __launch_bounds__(256) void k_prep(
        const float* __restrict__ E0, const float* __restrict__ Refs,
        const float* __restrict__ Mu,
        float4* __restrict__ FN, float4* __restrict__ FS,
        __hip_bfloat16* __restrict__ MQ) {
    __shared__ float muS[LL * LL];
    for (int i = threadIdx.x; i < LL * LL; i += 256) muS[i] = Mu[i];
    __syncthreads();

    int idx = blockIdx.x * 256 + threadIdx.x;      // b*N + n
    int b = idx / NNPX, n = idx % NNPX;

    const float* rb = Refs + (size_t)b * 3 * NNPX + n;
    float r0 = rb[0], r1 = rb[NNPX], r2 = rb[2 * NNPX];
    FN[idx] = make_float4(r0, r1, r2, 0.f);
    float g = -0.5f * (r0 * r0 + r1 * r1 + r2 * r2);
    FS[idx] = make_float4(g * LOG2E, r0 * LOG2E, r1 * LOG2E, r2 * LOG2E);

    const float* eb = E0 + (size_t)b * LL * NNPX + n;
    float x[LL];
    float mx = -1e30f;
    for (int l = 0; l < LL; ++l) { x[l] = -eb[(size_t)l * NNPX]; mx = fmaxf(mx, x[l]); }
    float s = 0.f;
    for (int l = 0; l < LL; ++l) { x[l] = __builtin_amdgcn_exp2f((x[l] - mx) * LOG2E); s += x[l]; }
    float rs = __builtin_amdgcn_rcpf(s);
    for (int l = 0; l < LL; ++l) x[l] *= rs;

    __hip_bfloat16* mq = MQ + (size_t)b * LL * NNPX + n;
    for (int k = 0; k < LL; ++k) {
        float a = 0.f;
        for (int l = 0; l < LL; ++l) a += muS[k * LL + l] * x[l];
        mq[(size_t)k * NNPX] = __float2bfloat16(a);
    }
}

// ---------------- accumulate via MFMA (msg + rowsum fused) ----------------
// grid (288, S): blockIdx.x = b*144 + n-tile (64 rows), blockIdx.y = s.
// Block handles CONTIGUOUS m-tiles [s*T, (s+1)*T), T = 144/S (even), tiles of 64.
__global__ __launch_bounds__(256, 8) void k_accum(
        const float4* __restrict__ FS, const float4* __restrict__ FN,
        const unsigned int* __restrict__ MQbf, float* __restrict__ Ppart, int S) {
    // SINGLE buffer: W: 64 n x 72 k bf16 (stride 72 = +8 pad); M: 21 l x 72 k
    // total 12.3 KB -> 8 blocks/CU static (wave-slot limit)
    __shared__ __align__(16) unsigned short Wlds[64 * 72];
    __shared__ __align__(16) unsigned short Mlds[21 * 72];

    int t = threadIdx.x;
    int rb = blockIdx.x;
    int s  = blockIdx.y;
    int b  = rb / 144;
    int n0 = (rb % 144) * 64;
    int wv = t >> 6, lane = t & 63;
    int lr = lane & 15, g = lane >> 4;

    // w-gen mapping (block-wide): thread owns n = ng + 16*i (i<4), m-quad mq
    int mq = t & 15;
    int ng = t >> 4;
    float4 fnr[4];
    for (int i = 0; i < 4; ++i) fnr[i] = FN[b * NNPX + n0 + ng + 16 * i];

    const int T  = 144 / S;
    const int t0 = s * T;
    const float4* fsb = FS + (size_t)b * NNPX;
    const unsigned int* mqb = MQbf + (size_t)b * LL * (NNPX / 2);

    // MQ stage ownership: dwords idx = t + 256*r (r<3), idx < 21*32 = 672
    int sl0 = t >> 5, sm0 = t & 31;                     // idx = t
    int sl1 = (t + 256) >> 5, sm1 = (t + 256) & 31;     // idx = t+256
    int sl2 = (t + 512) >> 5, sm2 = (t + 512) & 31;     // idx = t+512 (<672 iff t<160)

    f32x4 acc0 = {0.f, 0.f, 0.f, 0.f};   // C cols 0..15
    f32x4 acc1 = {0.f, 0.f, 0.f, 0.f};   // C cols 16..21 (+zero)

    short8 ones8, zero8;
    {
        u32x4 o = {0x3F803F80u, 0x3F803F80u, 0x3F803F80u, 0x3F803F80u};
        ones8 = __builtin_bit_cast(short8, o);
        u32x4 z = {0u, 0u, 0u, 0u};
        zero8 = __builtin_bit_cast(short8, z);
    }

    // two STATIC-NAMED prefetch register sets (rule #20: no runtime indexing)
    float4 fsA0, fsA1, fsA2, fsA3;  unsigned int mrA0, mrA1, mrA2;
    float4 fsB0, fsB1, fsB2, fsB3;  unsigned int mrB0, mrB1, mrB2;

    int row = wv * 16 + lr;

    auto LOADA = [&](int tile) {
        int m0 = (t0 + tile) * 64;
        fsA0 = fsb[m0 + 4 * mq + 0]; fsA1 = fsb[m0 + 4 * mq + 1];
        fsA2 = fsb[m0 + 4 * mq + 2]; fsA3 = fsb[m0 + 4 * mq + 3];
        int mo0 = (t0 + tile) * 32;
        mrA0 = mqb[(size_t)sl0 * (NNPX / 2) + mo0 + sm0];
        mrA1 = mqb[(size_t)sl1 * (NNPX / 2) + mo0 + sm1];
        if (t < 160) mrA2 = mqb[(size_t)sl2 * (NNPX / 2) + mo0 + sm2];
    };
    auto LOADB = [&](int tile) {
        int m0 = (t0 + tile) * 64;
        fsB0 = fsb[m0 + 4 * mq + 0]; fsB1 = fsb[m0 + 4 * mq + 1];
        fsB2 = fsb[m0 + 4 * mq + 2]; fsB3 = fsb[m0 + 4 * mq + 3];
        int mo0 = (t0 + tile) * 32;
        mrB0 = mqb[(size_t)sl0 * (NNPX / 2) + mo0 + sm0];
        mrB1 = mqb[(size_t)sl1 * (NNPX / 2) + mo0 + sm1];
        if (t < 160) mrB2 = mqb[(size_t)sl2 * (NNPX / 2) + mo0 + sm2];
    };
    auto STORE = [&](const float4& f0, const float4& f1,
                     const float4& f2, const float4& f3,
                     unsigned int m0r, unsigned int m1r, unsigned int m2r) {
        ((unsigned int*)&Mlds[sl0 * 72])[sm0] = m0r;
        ((unsigned int*)&Mlds[sl1 * 72])[sm1] = m1r;
        if (t < 160) ((unsigned int*)&Mlds[sl2 * 72])[sm2] = m2r;
        #pragma unroll
        for (int i = 0; i < 4; ++i) {
            float4 f = fnr[i];
            float w0 = __builtin_amdgcn_exp2f(f0.x + f.x * f0.y + f.y * f0.z + f.z * f0.w);
            float w1 = __builtin_amdgcn_exp2f(f1.x + f.x * f1.y + f.y * f1.z + f.z * f1.w);
            float w2 = __builtin_amdgcn_exp2f(f2.x + f.x * f2.y + f.y * f2.z + f.z * f2.w);
            float w3 = __builtin_amdgcn_exp2f(f3.x + f.x * f3.y + f.y * f3.z + f.z * f3.w);
            uint2 pk;
            pk.x = pk_bf16(w0, w1);
            pk.y = pk_bf16(w2, w3);
            *(uint2*)&Wlds[(ng + 16 * i) * 72 + 4 * mq] = pk;
        }
    };
    auto MFMA = [&]() {
        short8 a0  = *(const short8*)&Wlds[row * 72 + g * 8];
        short8 a1  = *(const short8*)&Wlds[row * 72 + g * 8 + 32];
        short8 b00 = *(const short8*)&Mlds[lr * 72 + g * 8];
        short8 b01 = *(const short8*)&Mlds[lr * 72 + g * 8 + 32];
        short8 b10, b11;
        if (lr < 5) {
            b10 = *(const short8*)&Mlds[(16 + lr) * 72 + g * 8];
            b11 = *(const short8*)&Mlds[(16 + lr) * 72 + g * 8 + 32];
        } else if (lr == 5) {
            b10 = ones8; b11 = ones8;     // rowsum column (l = 21)
        } else {
            b10 = zero8; b11 = zero8;
        }
        acc0 = __builtin_amdgcn_mfma_f32_16x16x32_bf16(a0, b00, acc0, 0, 0, 0);
        acc0 = __builtin_amdgcn_mfma_f32_16x16x32_bf16(a1, b01, acc0, 0, 0, 0);
        acc1 = __builtin_amdgcn_mfma_f32_16x16x32_bf16(a0, b10, acc1, 0, 0, 0);
        acc1 = __builtin_amdgcn_mfma_f32_16x16x32_bf16(a1, b11, acc1, 0, 0, 0);
    };

    // ---- prologue: tile 0 in flight in set A ----
    LOADA(0);

    // ---- main loop, 2 tiles per pass (T even), 2 thin barriers per tile ----
    // Single buffer is safe: each BARRIER's lgkmcnt(0) retires this wave's
    // ds_reads/writes before s_barrier, so no wave overwrites data another
    // wave still reads.
    for (int tt = 0; tt < T; tt += 2) {
        BARRIER();                      // all waves done reading (prev MFMA)
        LOADB(tt + 1);                  // issue next tile's globals early
        STORE(fsA0, fsA1, fsA2, fsA3, mrA0, mrA1, mrA2);   // tile tt
        BARRIER();                      // writes visible
        MFMA();                         // tile tt
        BARRIER();
        if (tt + 2 < T) LOADA(tt + 2);
        STORE(fsB0, fsB1, fsB2, fsB3, mrB0, mrB1, mrB2);   // tile tt+1
        BARRIER();
        MFMA();                         // tile tt+1
    }

    // epilogue: C layout col=lane&15, row=(lane>>4)*4+reg
    int col = lane & 15, qr = lane >> 4;
    float* pp = Ppart + ((size_t)(s * BB + b) * LP) * NNPX;
    for (int r = 0; r < 4; ++r) {
        int n = n0 + wv * 16 + qr * 4 + r;
        pp[(size_t)col * NNPX + n] = acc0[r];
        if (col < LP - 16) pp[(size_t)(16 + col) * NNPX + n] = acc1[r];
    }
}

// ---------------- reduce partials + softmax + Potts mix ----------------
template <bool LAST>
__global__ __launch_bounds__(256) void k_softmax(
        const float* __restrict__ E0, const float* __restrict__ Ppart,
        const float* __restrict__ Mu,
        __hip_bfloat16* __restrict__ MQ, float* __restrict__ Out, int S) {
    __shared__ float muS[LL * LL];
    for (int i = threadIdx.x; i < LL * LL; i += 256) muS[i] = Mu[i];
    __syncthreads();

    int idx = blockIdx.x * 256 + threadIdx.x;
    int b = idx / NNPX, n = idx % NNPX;

    float P[LP];
    for (int l = 0; l < LP; ++l) P[l] = 0.f;
    for (int s = 0; s < S; ++s) {
        const float* pp = Ppart + ((size_t)(s * BB + b) * LP) * NNPX + n;
        for (int l = 0; l < LP; ++l) P[l] += pp[(size_t)l * NNPX];
    }
    float rinv = __builtin_amdgcn_rcpf(P[LL]);   // rowsum from MFMA col 21

    const float* eb = E0 + (size_t)b * LL * NNPX + n;
    float mx = -1e30f;
    for (int l = 0; l < LL; ++l) {
        P[l] = -(eb[(size_t)l * NNPX] + P[l] * rinv);
        mx = fmaxf(mx, P[l]);
    }
    float ssum = 0.f;
    for (int l = 0; l < LL; ++l) { P[l] = __builtin_amdgcn_exp2f((P[l] - mx) * LOG2E); ssum += P[l]; }
    float rs = __builtin_amdgcn_rcpf(ssum);
    for (int l = 0; l < LL; ++l) P[l] *= rs;

    if (LAST) {
        float* ob = Out + (size_t)b * LL * NNPX + n;
        for (int l = 0; l < LL; ++l) ob[(size_t)l * NNPX] = P[l];
    } else {
        __hip_bfloat16* mq = MQ + (size_t)b * LL * NNPX + n;
        for (int k = 0; k < LL; ++k) {
            float a = 0.f;
            for (int l = 0; l < LL; ++l) a += muS[k * LL + l] * P[l];
            mq[(size_t)k * NNPX] = __float2bfloat16(a);
        }
    }
}

extern "C" void kernel_launch(void* const* d_in, const int* in_sizes, int n_in,
                              void* d_out, int out_size, void* d_ws, size_t ws_size,
                              hipStream_t stream) {
    const float* E0   = (const float*)d_in[0];
    const float* Refs = (const float*)d_in[1];
    const float* Mu   = (const float*)d_in[2];
    float* out = (float*)d_out;

    char* w = (char*)d_ws;
    size_t off = 0;
    auto alloc = [&](size_t bytes) {
        void* p = w + off;
        off += (bytes + 255) & ~(size_t)255;
        return p;
    };
    float4* FN     = (float4*)alloc((size_t)BB * NNPX * sizeof(float4));
    float4* FS     = (float4*)alloc((size_t)BB * NNPX * sizeof(float4));
    __hip_bfloat16* MQbf = (__hip_bfloat16*)alloc((size_t)BB * LL * NNPX * sizeof(__hip_bfloat16));

    // m-split S (divisor of 144, capped at 8) whose partial buffer fits in ws
    size_t per = (size_t)BB * LP * NNPX * sizeof(float);
    size_t avail = ws_size > off ? ws_size - off : 0;
    int Smax = (int)(avail / (per + 256));
    static const int divs[] = {8, 6, 4, 3, 2, 1};
    int S = 1;
    for (int i = 0; i < 6; ++i) if (divs[i] <= Smax) { S = divs[i]; break; }
    float* Ppart = (float*)alloc((size_t)S * per);

    k_prep<<<BB * NNPX / 256, 256, 0, stream>>>(E0, Refs, Mu, FN, FS, MQbf);
    for (int it = 0; it < NITERS; ++it) {
        k_accum<<<dim3(288, S), 256, 0, stream>>>(FS, FN, (const unsigned int*)MQbf, Ppart, S);
        if (it == NITERS - 1)
            k_softmax<true><<<BB * NNPX / 256, 256, 0, stream>>>(E0, Ppart, Mu, MQbf, out, S);
        else
            k_softmax<false><<<BB * NNPX / 256, 256, 0, stream>>>(E0, Ppart, Mu, MQbf, out, S);
    }
}

// Round 7
// 381.957 us; speedup vs baseline: 4.1021x; 4.1021x over previous
//
#include <hip/hip_runtime.h>
#include <hip/hip_bf16.h>

// CRF-as-RNN mean-field on MI355X. B=2, L=21, C=3, H=W=96, N=9216, NITERS=5.
//
// w[n][m] = exp2(gs[m] + f_n . fs[m]); per iter P[n][l] = sum_m w[n][m]*MQ[l][m]
// via bf16 MFMA 16x16x32. W generated on the fly into LDS (A-tile); MQ bf16
// staged as B-tile (single 12KB buffer -> 8 blocks/CU static). Mlds has 32
// rows: rows 0..20 = MQ tile, row 21 = const 1.0 (MFMA col 21 = rowsum(W)
// free), rows 22..31 = const 0 — initialized ONCE, so the MFMA block is
// branch-free and needs no ones/zero registers. Thin lgkm-only barriers
// (no vmcnt drain). DEPTH-1 register prefetch only: R5 proved 8 blocks/CU
// become resident (73% occ) but its launch_bounds(256,8) VGPR cap caused
// 1.8KB/thread scratch spill (1.09 GB HBM/dispatch). This round gets
// occupancy by keeping natural VGPR pressure < 64 instead of forcing it.
// msg = P/P[21]; Q = softmax_l(-(E0+msg)); MQ = Mu@Q (bf16).
//
// (R6 bench was a GPUAcquisitionTimeout; this is an unchanged resubmit.)

#define BB 2
#define LL 21
#define LP (LL + 1)   // Ppart rows: 21 msg cols + 1 rowsum col
#define NNPX 9216
#define NITERS 5
#define LOG2E 1.4426950408889634f

// raw barrier: waits LDS ops of this wave, syncs, does NOT drain vmcnt
#define BARRIER() asm volatile("s_waitcnt lgkmcnt(0)\n\ts_barrier" ::: "memory")

typedef __attribute__((ext_vector_type(8))) short short8;
typedef __attribute__((ext_vector_type(4))) float f32x4;

static __device__ inline unsigned int pk_bf16(float a, float b) {
    __hip_bfloat162 h = __float22bfloat162_rn(make_float2(a, b));
    unsigned int u;
    __builtin_memcpy(&u, &h, 4);
    return u;
}

// ---------------- prep: features + Q0 + MQ0(bf16) ----------------
__global__ __launch_bounds__(256) void k_prep(
        const float* __restrict__ E0, const float* __restrict__ Refs,
        const float* __restrict__ Mu,
        float4* __restrict__ FN, float4* __restrict__ FS,
        __hip_bfloat16* __restrict__ MQ) {
    __shared__ float muS[LL * LL];
    for (int i = threadIdx.x; i < LL * LL; i += 256) muS[i] = Mu[i];
    __syncthreads();

    int idx = blockIdx.x * 256 + threadIdx.x;      // b*N + n
    int b = idx / NNPX, n = idx % NNPX;

    const float* rb = Refs + (size_t)b * 3 * NNPX + n;
    float r0 = rb[0], r1 = rb[NNPX], r2 = rb[2 * NNPX];
    FN[idx] = make_float4(r0, r1, r2, 0.f);
    float g = -0.5f * (r0 * r0 + r1 * r1 + r2 * r2);
    FS[idx] = make_float4(g * LOG2E, r0 * LOG2E, r1 * LOG2E, r2 * LOG2E);

    const float* eb = E0 + (size_t)b * LL * NNPX + n;
    float x[LL];
    float mx = -1e30f;
    for (int l = 0; l < LL; ++l) { x[l] = -eb[(size_t)l * NNPX]; mx = fmaxf(mx, x[l]); }
    float s = 0.f;
    for (int l = 0; l < LL; ++l) { x[l] = __builtin_amdgcn_exp2f((x[l] - mx) * LOG2E); s += x[l]; }
    float rs = __builtin_amdgcn_rcpf(s);
    for (int l = 0; l < LL; ++l) x[l] *= rs;

    __hip_bfloat16* mq = MQ + (size_t)b * LL * NNPX + n;
    for (int k = 0; k < LL; ++k) {
        float a = 0.f;
        for (int l = 0; l < LL; ++l) a += muS[k * LL + l] * x[l];
        mq[(size_t)k * NNPX] = __float2bfloat16(a);
    }
}

// ---------------- accumulate via MFMA (msg + rowsum fused) ----------------
// grid (288, S): blockIdx.x = b*144 + n-tile (64 rows), blockIdx.y = s.
// Block handles CONTIGUOUS m-tiles [s*T, (s+1)*T), T = 144/S, tiles of 64.
__global__ __launch_bounds__(256, 4) void k_accum(
        const float4* __restrict__ FS, const float4* __restrict__ FN,
        const unsigned int* __restrict__ MQbf, float* __restrict__ Ppart, int S) {
    // W: 64 n x 72 k bf16 (stride 72 = +8 pad); M: 32 l x 72 k bf16
    // (rows 21..31 constant). Total ~13.7 KB -> 8 blocks/CU if VGPR <= 64.
    __shared__ __align__(16) unsigned short Wlds[64 * 72];
    __shared__ __align__(16) unsigned short Mlds[32 * 72];

    int t = threadIdx.x;
    int rb = blockIdx.x;
    int s  = blockIdx.y;
    int b  = rb / 144;
    int n0 = (rb % 144) * 64;
    int wv = t >> 6, lane = t & 63;
    int lr = lane & 15, g = lane >> 4;

    // one-time init of constant B rows: row 21 = 1.0 (rowsum), 22..31 = 0
    for (int i = t; i < 11 * 32; i += 256) {
        int r = 21 + (i >> 5), d = i & 31;
        ((unsigned int*)&Mlds[r * 72])[d] = (r == 21) ? 0x3F803F80u : 0u;
    }

    // w-gen mapping (block-wide): thread owns n = ng + 16*i (i<4), m-quad mq
    int mq = t & 15;
    int ng = t >> 4;
    float4 fnr[4];
    for (int i = 0; i < 4; ++i) fnr[i] = FN[b * NNPX + n0 + ng + 16 * i];

    const int T  = 144 / S;
    const int t0 = s * T;
    const float4* fsb = FS + (size_t)b * NNPX;
    const unsigned int* mqb = MQbf + (size_t)b * LL * (NNPX / 2);

    // MQ stage ownership: dwords idx = t + 256*r (r<3), idx < 21*32 = 672
    int sl0 = t >> 5, sm0 = t & 31;                     // idx = t
    int sl1 = (t + 256) >> 5, sm1 = (t + 256) & 31;     // idx = t+256
    int sl2 = (t + 512) >> 5, sm2 = (t + 512) & 31;     // idx = t+512 (<672 iff t<160)

    f32x4 acc0 = {0.f, 0.f, 0.f, 0.f};   // C cols 0..15
    f32x4 acc1 = {0.f, 0.f, 0.f, 0.f};   // C cols 16..21 (+zero)

    // single (depth-1) prefetch register set — keeps VGPR < 64
    float4 fsA0, fsA1, fsA2, fsA3;
    unsigned int mrA0, mrA1, mrA2;

    int row = wv * 16 + lr;

    auto LOADA = [&](int tile) {
        int m0 = (t0 + tile) * 64;
        fsA0 = fsb[m0 + 4 * mq + 0]; fsA1 = fsb[m0 + 4 * mq + 1];
        fsA2 = fsb[m0 + 4 * mq + 2]; fsA3 = fsb[m0 + 4 * mq + 3];
        int mo0 = (t0 + tile) * 32;
        mrA0 = mqb[(size_t)sl0 * (NNPX / 2) + mo0 + sm0];
        mrA1 = mqb[(size_t)sl1 * (NNPX / 2) + mo0 + sm1];
        if (t < 160) mrA2 = mqb[(size_t)sl2 * (NNPX / 2) + mo0 + sm2];
    };
    auto STORE = [&]() {
        ((unsigned int*)&Mlds[sl0 * 72])[sm0] = mrA0;
        ((unsigned int*)&Mlds[sl1 * 72])[sm1] = mrA1;
        if (t < 160) ((unsigned int*)&Mlds[sl2 * 72])[sm2] = mrA2;
        #pragma unroll
        for (int i = 0; i < 4; ++i) {
            float4 f = fnr[i];
            float w0 = __builtin_amdgcn_exp2f(fsA0.x + f.x * fsA0.y + f.y * fsA0.z + f.z * fsA0.w);
            float w1 = __builtin_amdgcn_exp2f(fsA1.x + f.x * fsA1.y + f.y * fsA1.z + f.z * fsA1.w);
            float w2 = __builtin_amdgcn_exp2f(fsA2.x + f.x * fsA2.y + f.y * fsA2.z + f.z * fsA2.w);
            float w3 = __builtin_amdgcn_exp2f(fsA3.x + f.x * fsA3.y + f.y * fsA3.z + f.z * fsA3.w);
            uint2 pk;
            pk.x = pk_bf16(w0, w1);
            pk.y = pk_bf16(w2, w3);
            *(uint2*)&Wlds[(ng + 16 * i) * 72 + 4 * mq] = pk;
        }
    };
    auto MFMA = [&]() {
        short8 a0  = *(const short8*)&Wlds[row * 72 + g * 8];
        short8 a1  = *(const short8*)&Wlds[row * 72 + g * 8 + 32];
        short8 b00 = *(const short8*)&Mlds[lr * 72 + g * 8];
        short8 b01 = *(const short8*)&Mlds[lr * 72 + g * 8 + 32];
        short8 b10 = *(const short8*)&Mlds[(16 + lr) * 72 + g * 8];
        short8 b11 = *(const short8*)&Mlds[(16 + lr) * 72 + g * 8 + 32];
        acc0 = __builtin_amdgcn_mfma_f32_16x16x32_bf16(a0, b00, acc0, 0, 0, 0);
        acc0 = __builtin_amdgcn_mfma_f32_16x16x32_bf16(a1, b01, acc0, 0, 0, 0);
        acc1 = __builtin_amdgcn_mfma_f32_16x16x32_bf16(a0, b10, acc1, 0, 0, 0);
        acc1 = __builtin_amdgcn_mfma_f32_16x16x32_bf16(a1, b11, acc1, 0, 0, 0);
    };

    // ---- prologue: tile 0 in flight ----
    LOADA(0);

    // ---- main loop: 2 thin barriers per tile; single LDS buffer is safe
    // because each BARRIER's lgkmcnt(0) retires this wave's LDS ops before
    // s_barrier, so no wave overwrites data another wave still reads. ----
    for (int tt = 0; tt < T; ++tt) {
        BARRIER();                  // all waves done reading tile tt-1
        STORE();                    // stage tile tt (vmcnt waits counted)
        if (tt + 1 < T) LOADA(tt + 1);   // issue next tile's globals
        BARRIER();                  // writes visible
        MFMA();                     // tile tt
    }

    // epilogue: C layout col=lane&15, row=(lane>>4)*4+reg
    int col = lane & 15, qr = lane >> 4;
    float* pp = Ppart + ((size_t)(s * BB + b) * LP) * NNPX;
    for (int r = 0; r < 4; ++r) {
        int n = n0 + wv * 16 + qr * 4 + r;
        pp[(size_t)col * NNPX + n] = acc0[r];
        if (col < LP - 16) pp[(size_t)(16 + col) * NNPX + n] = acc1[r];
    }
}

// ---------------- reduce partials + softmax + Potts mix ----------------
template <bool LAST>
__global__ __launch_bounds__(256) void k_softmax(
        const float* __restrict__ E0, const float* __restrict__ Ppart,
        const float* __restrict__ Mu,
        __hip_bfloat16* __restrict__ MQ, float* __restrict__ Out, int S) {
    __shared__ float muS[LL * LL];
    for (int i = threadIdx.x; i < LL * LL; i += 256) muS[i] = Mu[i];
    __syncthreads();

    int idx = blockIdx.x * 256 + threadIdx.x;
    int b = idx / NNPX, n = idx % NNPX;

    float P[LP];
    for (int l = 0; l < LP; ++l) P[l] = 0.f;
    for (int s = 0; s < S; ++s) {
        const float* pp = Ppart + ((size_t)(s * BB + b) * LP) * NNPX + n;
        for (int l = 0; l < LP; ++l) P[l] += pp[(size_t)l * NNPX];
    }
    float rinv = __builtin_amdgcn_rcpf(P[LL]);   // rowsum from MFMA col 21

    const float* eb = E0 + (size_t)b * LL * NNPX + n;
    float mx = -1e30f;
    for (int l = 0; l < LL; ++l) {
        P[l] = -(eb[(size_t)l * NNPX] + P[l] * rinv);
        mx = fmaxf(mx, P[l]);
    }
    float ssum = 0.f;
    for (int l = 0; l < LL; ++l) { P[l] = __builtin_amdgcn_exp2f((P[l] - mx) * LOG2E); ssum += P[l]; }
    float rs = __builtin_amdgcn_rcpf(ssum);
    for (int l = 0; l < LL; ++l) P[l] *= rs;

    if (LAST) {
        float* ob = Out + (size_t)b * LL * NNPX + n;
        for (int l = 0; l < LL; ++l) ob[(size_t)l * NNPX] = P[l];
    } else {
        __hip_bfloat16* mq = MQ + (size_t)b * LL * NNPX + n;
        for (int k = 0; k < LL; ++k) {
            float a = 0.f;
            for (int l = 0; l < LL; ++l) a += muS[k * LL + l] * P[l];
            mq[(size_t)k * NNPX] = __float2bfloat16(a);
        }
    }
}

extern "C" void kernel_launch(void* const* d_in, const int* in_sizes, int n_in,
                              void* d_out, int out_size, void* d_ws, size_t ws_size,
                              hipStream_t stream) {
    const float* E0   = (const float*)d_in[0];
    const float* Refs = (const float*)d_in[1];
    const float* Mu   = (const float*)d_in[2];
    float* out = (float*)d_out;

    char* w = (char*)d_ws;
    size_t off = 0;
    auto alloc = [&](size_t bytes) {
        void* p = w + off;
        off += (bytes + 255) & ~(size_t)255;
        return p;
    };
    float4* FN     = (float4*)alloc((size_t)BB * NNPX * sizeof(float4));
    float4* FS     = (float4*)alloc((size_t)BB * NNPX * sizeof(float4));
    __hip_bfloat16* MQbf = (__hip_bfloat16*)alloc((size_t)BB * LL * NNPX * sizeof(__hip_bfloat16));

    // m-split S (divisor of 144, capped at 8) whose partial buffer fits in ws
    size_t per = (size_t)BB * LP * NNPX * sizeof(float);
    size_t avail = ws_size > off ? ws_size - off : 0;
    int Smax = (int)(avail / (per + 256));
    static const int divs[] = {8, 6, 4, 3, 2, 1};
    int S = 1;
    for (int i = 0; i < 6; ++i) if (divs[i] <= Smax) { S = divs[i]; break; }
    float* Ppart = (float*)alloc((size_t)S * per);

    k_prep<<<BB * NNPX / 256, 256, 0, stream>>>(E0, Refs, Mu, FN, FS, MQbf);
    for (int it = 0; it < NITERS; ++it) {
        k_accum<<<dim3(288, S), 256, 0, stream>>>(FS, FN, (const unsigned int*)MQbf, Ppart, S);
        if (it == NITERS - 1)
            k_softmax<true><<<BB * NNPX / 256, 256, 0, stream>>>(E0, Ppart, Mu, MQbf, out, S);
        else
            k_softmax<false><<<BB * NNPX / 256, 256, 0, stream>>>(E0, Ppart, Mu, MQbf, out, S);
    }
}